// Round 6
// baseline (46.311 us; speedup 1.0000x reference)
//
#include <hip/hip_runtime.h>

// out[b,n,m] = qx[b,n] + qy[b,m] + sum_e (w[e]/2)*|px+pyc| + ob
//   relu(u) = (u+|u|)/2 splits into rank-1 part (qx,qy) + abs part.
// 2 kernels: k_proj (coeff inline via GLOBAL reads + projections + qx/qy),
//            k_main (f16 packed |.| contraction).

#define B_ 8
#define NM 256
#define D_ 128
#define DIN 1024

typedef _Float16 hh;
typedef _Float16 hh2 __attribute__((ext_vector_type(2)));
struct __attribute__((aligned(16))) H8 { hh2 h[4]; };

__device__ __forceinline__ float dot2acc(hh2 a, hh2 b, float c) {
#if __has_builtin(__builtin_amdgcn_fdot2)
    return __builtin_amdgcn_fdot2(a, b, c, false);
#else
    return c + (float)a.x * (float)b.x + (float)a.y * (float)b.y;
#endif
}

// ---- K1: coeff (src=0 blocks, global-read dots) + px/pyc + qx/qy ----
// grid 256: bsrc = bx>>4 (b = bsrc>>1, src = bsrc&1), rowtile = bx&15.
// block 512 = 8 waves; GEMM: kq = t>>7 k-quarter, tt = t&127 (er=tt&31, rr=tt>>5).
__global__ __launch_bounds__(512) void k_proj(
    const float* __restrict__ X, const float* __restrict__ Y,
    const float* __restrict__ wts, const float* __restrict__ Aw,
    const float* __restrict__ Ab, const float* __restrict__ lin_w,
    const float* __restrict__ lin_b, const float* __restrict__ out_w,
    hh* __restrict__ px, hh* __restrict__ pyc,
    float* __restrict__ qx, float* __restrict__ qy)
{
    __shared__ __align__(16) char smem[66816];
    float* S   = (float*)smem;               // [16][132]   8448 B
    float* Wl  = (float*)(smem + 8448);      // [128][66]  33792 B
    float* RED = (float*)(smem + 42240);     // 3*2048 f   24576 B
    __shared__ float cofS[128];

    const int bx = blockIdx.x;
    const int bsrc = bx >> 4, b = bsrc >> 1, src = bsrc & 1;
    const int r0 = (bx & 15) * 16;
    const int t = threadIdx.x;

    // stage S raw: 512 float4, one per thread
    const float* Sg = (src ? Y : X) + (size_t)(b * NM + r0) * D_;
    *(float4*)(&S[(t >> 5) * 132 + (t & 31) * 4]) = ((const float4*)Sg)[t];

    if (!src) {
        // coeff[e] = tanh(wts[b,:].Aw[e,:] + Ab[e]); e = w*16+(l>>2), h = l&3,
        // partial over k in [h*256, h*256+256). All reads GLOBAL (L2/L3).
        const int w = t >> 6, l = t & 63;
        const int e = w * 16 + (l >> 2), h = l & 3;
        const float4* wr = (const float4*)(wts + b * DIN + h * 256);
        const float4* ar = (const float4*)(Aw + (size_t)e * DIN + h * 256);
        float s = 0.f;
#pragma unroll 8
        for (int j = 0; j < 64; ++j) {
            float4 a = ar[j], ww = wr[j];
            s += a.x * ww.x + a.y * ww.y + a.z * ww.z + a.w * ww.w;
        }
        s += __shfl_xor(s, 1, 64);
        s += __shfl_xor(s, 2, 64);
        if (h == 0) cofS[e] = tanhf(s + Ab[e]);
    }
    __syncthreads();
    if (!src) {
        // scale own S quad by coeff (same location this thread wrote)
        float4* sp = (float4*)(&S[(t >> 5) * 132 + (t & 31) * 4]);
        float4 v = *sp;
        float4 c = ((const float4*)cofS)[t & 31];
        v.x *= c.x; v.y *= c.y; v.z *= c.z; v.w *= c.w;
        *sp = v;
    }

    const int kq = t >> 7, tt = t & 127;
    const int er = tt & 31, rr = tt >> 5;
    float acc[4][4] = {};

    for (int p = 0; p < 2; ++p) {
        __syncthreads();
        for (int ii = t; ii < 2048; ii += 512) {
            int e = ii >> 4, k4 = ii & 15;
            float4 g = *(const float4*)(lin_w + (size_t)e * 256 + src * 128 +
                                        p * 64 + k4 * 4);
            float* wp = &Wl[e * 66 + k4 * 4];
            *(float2*)(wp)     = make_float2(g.x, g.y);
            *(float2*)(wp + 2) = make_float2(g.z, g.w);
        }
        __syncthreads();
#pragma unroll
        for (int kt = 0; kt < 16; kt += 4) {
            const int kl = kq * 16 + kt;
            const int kg = p * 64 + kl;
            float4 a[4]; float2 w0[4], w1[4];
#pragma unroll
            for (int i = 0; i < 4; ++i)
                a[i] = *(const float4*)(&S[(rr + 4 * i) * 132 + kg]);
#pragma unroll
            for (int j = 0; j < 4; ++j) {
                const float* wp = &Wl[(er + 32 * j) * 66 + kl];
                w0[j] = *(const float2*)(wp);
                w1[j] = *(const float2*)(wp + 2);
            }
#pragma unroll
            for (int i = 0; i < 4; ++i)
#pragma unroll
                for (int j = 0; j < 4; ++j)
                    acc[i][j] += a[i].x * w0[j].x + a[i].y * w0[j].y +
                                 a[i].z * w1[j].x + a[i].w * w1[j].y;
        }
    }

    __syncthreads();
    if (kq) {
        float* R = RED + (size_t)(kq - 1) * 2048;
#pragma unroll
        for (int i = 0; i < 4; ++i)
#pragma unroll
            for (int j = 0; j < 4; ++j) R[(i * 4 + j) * 128 + tt] = acc[i][j];
    }
    __syncthreads();
    if (kq == 0) {
#pragma unroll
        for (int q = 0; q < 3; ++q)
#pragma unroll
            for (int i = 0; i < 4; ++i)
#pragma unroll
                for (int j = 0; j < 4; ++j)
                    acc[i][j] += RED[(size_t)q * 2048 + (i * 4 + j) * 128 + tt];
        hh* Pg = (src ? pyc : px) + (size_t)(b * NM + r0) * D_;
        float qpart[4] = {0.f, 0.f, 0.f, 0.f};
#pragma unroll
        for (int i = 0; i < 4; ++i)
#pragma unroll
            for (int j = 0; j < 4; ++j) {
                int e = er + 32 * j;
                float v = acc[i][j];
                if (src) v += lin_b[e];
                Pg[(rr + 4 * i) * D_ + e] = (hh)v;
                qpart[i] = fmaf(0.5f * out_w[e], v, qpart[i]);
            }
        float* Qg = (src ? qy : qx) + b * NM + r0;
#pragma unroll
        for (int i = 0; i < 4; ++i) {
            float s = qpart[i];
#pragma unroll
            for (int d2 = 16; d2; d2 >>= 1) s += __shfl_xor(s, d2, 64);
            if (er == 0) Qg[rr + 4 * i] = s;
        }
    }
}

// ---- K2: main |.| contraction, f16 packed, e-split-4. grid 256, block 512 ----
__global__ __launch_bounds__(512) void k_main(
    const hh* __restrict__ px, const hh* __restrict__ pyc,
    const float* __restrict__ qx, const float* __restrict__ qy,
    const float* __restrict__ out_w, const float* __restrict__ out_b,
    float* __restrict__ out) {
    __shared__ hh PXs[64 * 136];      // stride 272 B (16B-aligned rows)
    __shared__ hh PYs[32 * 136];
    __shared__ float RED[48 * 128];
    __shared__ hh WHs[128];
    __shared__ float QXl[64], QYl[32];

    const int bx = blockIdx.x;
    const int b = bx & 7, tile = bx >> 3;
    const int n0 = (tile >> 3) * 64, m0 = (tile & 7) * 32;
    const int t = threadIdx.x;

    const uint4* pxg = (const uint4*)(px + (size_t)(b * NM + n0) * D_);
    for (int i = t; i < 1024; i += 512)
        *(uint4*)(&PXs[(i >> 4) * 136 + (i & 15) * 8]) = pxg[i];
    const uint4* pyg = (const uint4*)(pyc + (size_t)(b * NM + m0) * D_);
    if (t < 512)
        *(uint4*)(&PYs[(t >> 4) * 136 + (t & 15) * 8]) = pyg[t];
    if (t < 128) WHs[t] = (hh)(0.5f * out_w[t]);
    else if (t < 192) QXl[t - 128] = qx[b * NM + n0 + (t - 128)];
    else if (t < 224) QYl[t - 192] = qy[b * NM + m0 + (t - 192)];
    __syncthreads();

    const int w = t >> 6, eq = w & 3, half = w >> 2;
    const int s = half * 64 + (t & 63);
    const int nr = s >> 3, mr = s & 7;
    const int e0 = eq * 32;

    hh2 wv[16];
#pragma unroll
    for (int q = 0; q < 16; ++q) wv[q] = *(const hh2*)(&WHs[e0 + 2 * q]);

    float acc[4][4] = {};
#pragma unroll
    for (int es = 0; es < 4; ++es) {          // 8 e per step
        H8 xa[4], ya[4];
#pragma unroll
        for (int i = 0; i < 4; ++i)
            xa[i] = *(const H8*)(&PXs[(nr + 16 * i) * 136 + e0 + es * 8]);
#pragma unroll
        for (int j = 0; j < 4; ++j)
            ya[j] = *(const H8*)(&PYs[(mr + 8 * j) * 136 + e0 + es * 8]);
#pragma unroll
        for (int i = 0; i < 4; ++i)
#pragma unroll
            for (int j = 0; j < 4; ++j)
#pragma unroll
                for (int p = 0; p < 4; ++p) {
                    hh2 u = xa[i].h[p] + ya[j].h[p];
                    unsigned uu;
                    __builtin_memcpy(&uu, &u, 4);
                    uu &= 0x7fff7fffu;
                    hh2 au;
                    __builtin_memcpy(&au, &uu, 4);
                    acc[i][j] = dot2acc(au, wv[es * 4 + p], acc[i][j]);
                }
    }

    if (eq) {
#pragma unroll
        for (int i = 0; i < 4; ++i)
#pragma unroll
            for (int j = 0; j < 4; ++j)
                RED[((eq - 1) * 16 + i * 4 + j) * 128 + s] = acc[i][j];
    }
    __syncthreads();
    if (eq == 0) {
        const float ob = out_b[0];
        float* og = out + (size_t)b * NM * NM;
#pragma unroll
        for (int i = 0; i < 4; ++i) {
            float qn = QXl[nr + 16 * i];
#pragma unroll
            for (int j = 0; j < 4; ++j) {
                float v = acc[i][j];
#pragma unroll
                for (int p = 0; p < 3; ++p)
                    v += RED[(p * 16 + i * 4 + j) * 128 + s];
                og[(n0 + nr + 16 * i) * NM + m0 + mr + 8 * j] =
                    v + qn + QYl[mr + 8 * j] + ob;
            }
        }
    }
}

extern "C" void kernel_launch(void* const* d_in, const int* in_sizes, int n_in,
                              void* d_out, int out_size, void* d_ws, size_t ws_size,
                              hipStream_t stream) {
    const float* X      = (const float*)d_in[0];
    const float* Y      = (const float*)d_in[1];
    const float* wts    = (const float*)d_in[2];
    const float* A_w    = (const float*)d_in[3];
    const float* A_b    = (const float*)d_in[4];
    const float* lin_w  = (const float*)d_in[5];
    const float* lin_b  = (const float*)d_in[6];
    const float* out_w  = (const float*)d_in[7];
    const float* out_b  = (const float*)d_in[8];
    float* out = (float*)d_out;

    hh*    px    = (hh*)d_ws;                       // 8*256*128 halves
    hh*    pyc   = px + B_ * NM * D_;               // 8*256*128 halves
    float* qx    = (float*)(pyc + B_ * NM * D_);    // 2048 f
    float* qy    = qx + 2048;                       // 2048 f

    k_proj<<<dim3(256), 512, 0, stream>>>(X, Y, wts, A_w, A_b, lin_w, lin_b,
                                          out_w, px, pyc, qx, qy);
    k_main<<<dim3(256), 512, 0, stream>>>(px, pyc, qx, qy, out_w, out_b, out);
}

// Round 7
// 21.020 us; speedup vs baseline: 2.2032x; 2.2032x over previous
//
#include <hip/hip_runtime.h>

// out[b,n,m] = qx[b,n] + qy[b,m] + sum_e (w[e]/2)*|px+pyc| + ob
//   relu(u) = (u+|u|)/2 splits into rank-1 part (qx,qy) + abs part.
// 3 kernels:
//   k1: blocks 0..127 = coeff (R5's proven wave shape); blocks 128..255 = pyc+qy
//   k2: px+qx (needs coeff)
//   k3: main |.| contraction (unchanged from R5)
// Projection GEMMs are f16 staged + v_dot2_f32_f16.

#define B_ 8
#define NM 256
#define D_ 128
#define DIN 1024

typedef _Float16 hh;
typedef _Float16 hh2 __attribute__((ext_vector_type(2)));
struct __attribute__((aligned(8)))  H4 { hh2 h[2]; };
struct __attribute__((aligned(16))) H8 { hh2 h[4]; };

__device__ __forceinline__ float dot2acc(hh2 a, hh2 b, float c) {
#if __has_builtin(__builtin_amdgcn_fdot2)
    return __builtin_amdgcn_fdot2(a, b, c, false);
#else
    return c + (float)a.x * (float)b.x + (float)a.y * (float)b.y;
#endif
}

__device__ __forceinline__ void st_h4(hh* p, float4 v) {
    H4 h;
    h.h[0] = hh2{(hh)v.x, (hh)v.y};
    h.h[1] = hh2{(hh)v.z, (hh)v.w};
    *(H4*)p = h;
}

// ---- K1: coeff (blocks 0..127) + pyc/qy (blocks 128..255). block 512 ----
__global__ __launch_bounds__(512) void k1(
    const float* __restrict__ Y, const float* __restrict__ wts,
    const float* __restrict__ Aw, const float* __restrict__ Ab,
    const float* __restrict__ lin_w, const float* __restrict__ lin_b,
    const float* __restrict__ out_w, float* __restrict__ coeff,
    hh* __restrict__ pyc, float* __restrict__ qy)
{
    __shared__ hh S[16 * 136];        //  4352 B
    __shared__ hh Wl[128 * 132];      // 33792 B (stride 132 halves: 2-way free)
    __shared__ float RED[3 * 2048];   // 24576 B

    const int bx = blockIdx.x;
    const int t = threadIdx.x;

    if (bx < 128) {
        // coeff: 8 waves/block, one (b,e) job per wave (R5 shape, proven ~1.3us)
        const int w = t >> 6, lane = t & 63;
        const int job = bx * 8 + w;               // 0..1023
        const int b = job >> 7, e = job & 127;
        const float4* wr = (const float4*)(wts + b * DIN);
        const float4* ar = (const float4*)(Aw + (size_t)e * DIN);
        float s = 0.f;
#pragma unroll
        for (int i = 0; i < 4; ++i) {
            float4 wv = wr[i * 64 + lane];
            float4 av = ar[i * 64 + lane];
            s += wv.x * av.x + wv.y * av.y + wv.z * av.z + wv.w * av.w;
        }
#pragma unroll
        for (int d = 32; d; d >>= 1) s += __shfl_xor(s, d, 64);
        if (lane == 0) coeff[b * 128 + e] = tanhf(s + Ab[e]);
        return;
    }

    // ---- pyc blocks ----
    const int bb = bx - 128;                       // 0..127
    const int b = bb >> 4, r0 = (bb & 15) * 16;

    // stage S = Y tile (16x128), f16
    {
        float4 v = ((const float4*)(Y + (size_t)(b * NM + r0) * D_))[t];
        st_h4(&S[(t >> 5) * 136 + (t & 31) * 4], v);
    }
    // stage Wl = lin_w[e][128 + k], f16, stride 132
    for (int ii = t; ii < 4096; ii += 512) {
        int e = ii >> 5, k4 = ii & 31;
        float4 g = *(const float4*)(lin_w + (size_t)e * 256 + 128 + k4 * 4);
        st_h4(&Wl[e * 132 + k4 * 4], g);
    }
    __syncthreads();

    const int kq = t >> 7, tt = t & 127;
    const int er = tt & 31, rr = tt >> 5;
    float acc[4][4] = {};
#pragma unroll
    for (int kt = 0; kt < 32; kt += 8) {
        const int kg = kq * 32 + kt;
        H8 a[4]; H4 w0[4], w1[4];
#pragma unroll
        for (int i = 0; i < 4; ++i)
            a[i] = *(const H8*)(&S[(rr + 4 * i) * 136 + kg]);
#pragma unroll
        for (int j = 0; j < 4; ++j) {
            const hh* wp = &Wl[(er + 32 * j) * 132 + kg];
            w0[j] = *(const H4*)(wp);
            w1[j] = *(const H4*)(wp + 4);
        }
#pragma unroll
        for (int i = 0; i < 4; ++i)
#pragma unroll
            for (int j = 0; j < 4; ++j) {
                float c = acc[i][j];
                c = dot2acc(a[i].h[0], w0[j].h[0], c);
                c = dot2acc(a[i].h[1], w0[j].h[1], c);
                c = dot2acc(a[i].h[2], w1[j].h[0], c);
                c = dot2acc(a[i].h[3], w1[j].h[1], c);
                acc[i][j] = c;
            }
    }

    __syncthreads();
    if (kq) {
        float* R = RED + (size_t)(kq - 1) * 2048;
#pragma unroll
        for (int i = 0; i < 4; ++i)
#pragma unroll
            for (int j = 0; j < 4; ++j) R[(i * 4 + j) * 128 + tt] = acc[i][j];
    }
    __syncthreads();
    if (kq == 0) {
#pragma unroll
        for (int q = 0; q < 3; ++q)
#pragma unroll
            for (int i = 0; i < 4; ++i)
#pragma unroll
                for (int j = 0; j < 4; ++j)
                    acc[i][j] += RED[(size_t)q * 2048 + (i * 4 + j) * 128 + tt];
        hh* Pg = pyc + (size_t)(b * NM + r0) * D_;
        float qpart[4] = {0.f, 0.f, 0.f, 0.f};
#pragma unroll
        for (int i = 0; i < 4; ++i)
#pragma unroll
            for (int j = 0; j < 4; ++j) {
                int e = er + 32 * j;
                float v = acc[i][j] + lin_b[e];
                Pg[(rr + 4 * i) * D_ + e] = (hh)v;
                qpart[i] = fmaf(0.5f * out_w[e], v, qpart[i]);
            }
        float* Qg = qy + b * NM + r0;
#pragma unroll
        for (int i = 0; i < 4; ++i) {
            float s = qpart[i];
#pragma unroll
            for (int d2 = 16; d2; d2 >>= 1) s += __shfl_xor(s, d2, 64);
            if (er == 0) Qg[rr + 4 * i] = s;
        }
    }
}

// ---- K2: px + qx. grid 256 (8-row tiles), block 512 ----
__global__ __launch_bounds__(512) void k2(
    const float* __restrict__ X, const float* __restrict__ coeff,
    const float* __restrict__ lin_w, const float* __restrict__ out_w,
    hh* __restrict__ px, float* __restrict__ qx)
{
    __shared__ hh S[8 * 136];         //  2176 B
    __shared__ hh Wl[128 * 132];      // 33792 B
    __shared__ float RED[3 * 1024];   // 12288 B

    const int bx = blockIdx.x;
    const int b = bx >> 5, r0 = (bx & 31) * 8;
    const int t = threadIdx.x;

    // stage S = X tile (8x128) * coeff, f16
    if (t < 256) {
        float4 v = ((const float4*)(X + (size_t)(b * NM + r0) * D_))[t];
        float4 c = ((const float4*)(coeff + b * 128))[t & 31];
        v.x *= c.x; v.y *= c.y; v.z *= c.z; v.w *= c.w;
        st_h4(&S[(t >> 5) * 136 + (t & 31) * 4], v);
    }
    for (int ii = t; ii < 4096; ii += 512) {
        int e = ii >> 5, k4 = ii & 31;
        float4 g = *(const float4*)(lin_w + (size_t)e * 256 + k4 * 4);
        st_h4(&Wl[e * 132 + k4 * 4], g);
    }
    __syncthreads();

    const int kq = t >> 7, tt = t & 127;
    const int er = tt & 31, rr = tt >> 5;    // rows = rr + 4i, i<2
    float acc[2][4] = {};
#pragma unroll
    for (int kt = 0; kt < 32; kt += 8) {
        const int kg = kq * 32 + kt;
        H8 a[2]; H4 w0[4], w1[4];
#pragma unroll
        for (int i = 0; i < 2; ++i)
            a[i] = *(const H8*)(&S[(rr + 4 * i) * 136 + kg]);
#pragma unroll
        for (int j = 0; j < 4; ++j) {
            const hh* wp = &Wl[(er + 32 * j) * 132 + kg];
            w0[j] = *(const H4*)(wp);
            w1[j] = *(const H4*)(wp + 4);
        }
#pragma unroll
        for (int i = 0; i < 2; ++i)
#pragma unroll
            for (int j = 0; j < 4; ++j) {
                float c = acc[i][j];
                c = dot2acc(a[i].h[0], w0[j].h[0], c);
                c = dot2acc(a[i].h[1], w0[j].h[1], c);
                c = dot2acc(a[i].h[2], w1[j].h[0], c);
                c = dot2acc(a[i].h[3], w1[j].h[1], c);
                acc[i][j] = c;
            }
    }

    __syncthreads();
    if (kq) {
        float* R = RED + (size_t)(kq - 1) * 1024;
#pragma unroll
        for (int i = 0; i < 2; ++i)
#pragma unroll
            for (int j = 0; j < 4; ++j) R[(i * 4 + j) * 128 + tt] = acc[i][j];
    }
    __syncthreads();
    if (kq == 0) {
#pragma unroll
        for (int q = 0; q < 3; ++q)
#pragma unroll
            for (int i = 0; i < 2; ++i)
#pragma unroll
                for (int j = 0; j < 4; ++j)
                    acc[i][j] += RED[(size_t)q * 1024 + (i * 4 + j) * 128 + tt];
        hh* Pg = px + (size_t)(b * NM + r0) * D_;
        float qpart[2] = {0.f, 0.f};
#pragma unroll
        for (int i = 0; i < 2; ++i)
#pragma unroll
            for (int j = 0; j < 4; ++j) {
                int e = er + 32 * j;
                float v = acc[i][j];
                Pg[(rr + 4 * i) * D_ + e] = (hh)v;
                qpart[i] = fmaf(0.5f * out_w[e], v, qpart[i]);
            }
        float* Qg = qx + b * NM + r0;
#pragma unroll
        for (int i = 0; i < 2; ++i) {
            float s = qpart[i];
#pragma unroll
            for (int d2 = 16; d2; d2 >>= 1) s += __shfl_xor(s, d2, 64);
            if (er == 0) Qg[rr + 4 * i] = s;
        }
    }
}

// ---- K3: main |.| contraction, f16 packed, e-split-4 (unchanged from R5) ----
__global__ __launch_bounds__(512) void k_main(
    const hh* __restrict__ px, const hh* __restrict__ pyc,
    const float* __restrict__ qx, const float* __restrict__ qy,
    const float* __restrict__ out_w, const float* __restrict__ out_b,
    float* __restrict__ out) {
    __shared__ hh PXs[64 * 136];
    __shared__ hh PYs[32 * 136];
    __shared__ float RED[48 * 128];
    __shared__ hh WHs[128];
    __shared__ float QXl[64], QYl[32];

    const int bx = blockIdx.x;
    const int b = bx & 7, tile = bx >> 3;
    const int n0 = (tile >> 3) * 64, m0 = (tile & 7) * 32;
    const int t = threadIdx.x;

    const uint4* pxg = (const uint4*)(px + (size_t)(b * NM + n0) * D_);
    for (int i = t; i < 1024; i += 512)
        *(uint4*)(&PXs[(i >> 4) * 136 + (i & 15) * 8]) = pxg[i];
    const uint4* pyg = (const uint4*)(pyc + (size_t)(b * NM + m0) * D_);
    if (t < 512)
        *(uint4*)(&PYs[(t >> 4) * 136 + (t & 15) * 8]) = pyg[t];
    if (t < 128) WHs[t] = (hh)(0.5f * out_w[t]);
    else if (t < 192) QXl[t - 128] = qx[b * NM + n0 + (t - 128)];
    else if (t < 224) QYl[t - 192] = qy[b * NM + m0 + (t - 192)];
    __syncthreads();

    const int w = t >> 6, eq = w & 3, half = w >> 2;
    const int s = half * 64 + (t & 63);
    const int nr = s >> 3, mr = s & 7;
    const int e0 = eq * 32;

    hh2 wv[16];
#pragma unroll
    for (int q = 0; q < 16; ++q) wv[q] = *(const hh2*)(&WHs[e0 + 2 * q]);

    float acc[4][4] = {};
#pragma unroll
    for (int es = 0; es < 4; ++es) {          // 8 e per step
        H8 xa[4], ya[4];
#pragma unroll
        for (int i = 0; i < 4; ++i)
            xa[i] = *(const H8*)(&PXs[(nr + 16 * i) * 136 + e0 + es * 8]);
#pragma unroll
        for (int j = 0; j < 4; ++j)
            ya[j] = *(const H8*)(&PYs[(mr + 8 * j) * 136 + e0 + es * 8]);
#pragma unroll
        for (int i = 0; i < 4; ++i)
#pragma unroll
            for (int j = 0; j < 4; ++j)
#pragma unroll
                for (int p = 0; p < 4; ++p) {
                    hh2 u = xa[i].h[p] + ya[j].h[p];
                    unsigned uu;
                    __builtin_memcpy(&uu, &u, 4);
                    uu &= 0x7fff7fffu;
                    hh2 au;
                    __builtin_memcpy(&au, &uu, 4);
                    acc[i][j] = dot2acc(au, wv[es * 4 + p], acc[i][j]);
                }
    }

    if (eq) {
#pragma unroll
        for (int i = 0; i < 4; ++i)
#pragma unroll
            for (int j = 0; j < 4; ++j)
                RED[((eq - 1) * 16 + i * 4 + j) * 128 + s] = acc[i][j];
    }
    __syncthreads();
    if (eq == 0) {
        const float ob = out_b[0];
        float* og = out + (size_t)b * NM * NM;
#pragma unroll
        for (int i = 0; i < 4; ++i) {
            float qn = QXl[nr + 16 * i];
#pragma unroll
            for (int j = 0; j < 4; ++j) {
                float v = acc[i][j];
#pragma unroll
                for (int p = 0; p < 3; ++p)
                    v += RED[(p * 16 + i * 4 + j) * 128 + s];
                og[(n0 + nr + 16 * i) * NM + m0 + mr + 8 * j] =
                    v + qn + QYl[mr + 8 * j] + ob;
            }
        }
    }
}

extern "C" void kernel_launch(void* const* d_in, const int* in_sizes, int n_in,
                              void* d_out, int out_size, void* d_ws, size_t ws_size,
                              hipStream_t stream) {
    const float* X      = (const float*)d_in[0];
    const float* Y      = (const float*)d_in[1];
    const float* wts    = (const float*)d_in[2];
    const float* A_w    = (const float*)d_in[3];
    const float* A_b    = (const float*)d_in[4];
    const float* lin_w  = (const float*)d_in[5];
    const float* lin_b  = (const float*)d_in[6];
    const float* out_w  = (const float*)d_in[7];
    const float* out_b  = (const float*)d_in[8];
    float* out = (float*)d_out;

    hh*    px    = (hh*)d_ws;                       // 8*256*128 halves
    hh*    pyc   = px + B_ * NM * D_;               // 8*256*128 halves
    float* qx    = (float*)(pyc + B_ * NM * D_);    // 2048 f
    float* qy    = qx + 2048;                       // 2048 f
    float* coeff = qy + 2048;                       // 1024 f

    k1<<<dim3(256), 512, 0, stream>>>(Y, wts, A_w, A_b, lin_w, lin_b, out_w,
                                      coeff, pyc, qy);
    k2<<<dim3(256), 512, 0, stream>>>(X, coeff, lin_w, out_w, px, qx);
    k_main<<<dim3(256), 512, 0, stream>>>(px, pyc, qx, qy, out_w, out_b, out);
}